// Round 20
// baseline (41.072 us; speedup 1.0000x reference)
//
#include <hip/hip_runtime.h>
#include <math.h>

// ---- DCT constants (fp32) ----
#define A0c 0.35355339059327373f
#define C1c 0.4903926402016152f
#define C2c 0.46193976625564337f
#define C3c 0.41573480615127262f
#define C5c 0.27778511650980114f
#define C6c 0.19134171618254492f
#define C7c 0.09754516100806417f

#define IMG_W 512
#define IMG_HW (512 * 512)

typedef float f8v __attribute__((ext_vector_type(8)));
typedef float f2v __attribute__((ext_vector_type(2)));

// base JPEG tables, ORIGINAL orientation (QUALITY=50 -> scaled == base)
__device__ const float QLUM[64] = {
    16,11,10,16,24,40,51,61,  12,12,14,19,26,58,60,55,
    14,13,16,24,40,57,69,56,  14,17,22,29,51,87,80,62,
    18,22,37,56,68,109,103,77, 24,35,55,64,81,104,113,92,
    49,64,78,87,103,121,120,101, 72,92,95,98,112,100,103,99};
__device__ const float QCHR[64] = {
    17,18,24,47,99,99,99,99,  18,21,26,66,99,99,99,99,
    24,26,56,99,99,99,99,99,  47,66,99,99,99,99,99,99,
    99,99,99,99,99,99,99,99,  99,99,99,99,99,99,99,99,
    99,99,99,99,99,99,99,99,  99,99,99,99,99,99,99,99};

// In-place 8-point DCT-II on PAIRS (R16-proven: maps to v_pk_*_f32)
__device__ __forceinline__ void fdct8p(f2v v[8]) {
    f2v s0 = v[0] + v[7], s1 = v[1] + v[6], s2 = v[2] + v[5], s3 = v[3] + v[4];
    f2v d0 = v[0] - v[7], d1 = v[1] - v[6], d2 = v[2] - v[5], d3 = v[3] - v[4];
    f2v e0 = s0 + s3, e1 = s1 + s2, f0 = s0 - s3, f1 = s1 - s2;
    v[0] = A0c * (e0 + e1);
    v[4] = A0c * (e0 - e1);
    v[2] = C2c * f0 + C6c * f1;
    v[6] = C6c * f0 - C2c * f1;
    v[1] = C1c * d0 + C3c * d1 + C5c * d2 + C7c * d3;
    v[3] = C3c * d0 - C7c * d1 - C1c * d2 - C5c * d3;
    v[5] = C5c * d0 - C1c * d1 + C7c * d2 + C3c * d3;
    v[7] = C7c * d0 - C5c * d1 + C3c * d2 - C1c * d3;
}

__device__ __forceinline__ void idct8p(f2v v[8]) {
    f2v g0 = v[0], g1 = v[1], g2 = v[2], g3 = v[3];
    f2v g4 = v[4], g5 = v[5], g6 = v[6], g7 = v[7];
    f2v ep = A0c * (g0 + g4), em = A0c * (g0 - g4);
    f2v t26a = C2c * g2 + C6c * g6;
    f2v t26b = C6c * g2 - C2c * g6;
    f2v e0 = ep + t26a, e1 = em + t26b, e2 = em - t26b, e3 = ep - t26a;
    f2v o0 = C1c * g1 + C3c * g3 + C5c * g5 + C7c * g7;
    f2v o1 = C3c * g1 - C7c * g3 - C1c * g5 - C5c * g7;
    f2v o2 = C5c * g1 - C1c * g3 + C7c * g5 + C3c * g7;
    f2v o3 = C7c * g1 - C5c * g3 + C3c * g5 - C1c * g7;
    v[0] = e0 + o0; v[7] = e0 - o0;
    v[1] = e1 + o1; v[6] = e1 - o1;
    v[2] = e2 + o2; v[5] = e2 - o2;
    v[3] = e3 + o3; v[4] = e3 - o3;
}

// soft quantize-dequantize on a pair (R16-proven)
#define K_EXP2 43.2808512266689f
__device__ __forceinline__ f2v softq2(f2v x, float qh, float rq) {
    f2v d = x * rq;
    f2v rn; rn[0] = rintf(d[0]); rn[1] = rintf(d[1]);
    f2v t = d - rn;
    f2v e2; e2[0] = __builtin_amdgcn_exp2f(K_EXP2 * t[0]);
            e2[1] = __builtin_amdgcn_exp2f(K_EXP2 * t[1]);
    f2v num = e2 - 1.0f;
    f2v th; th[0] = num[0] * __builtin_amdgcn_rcpf(e2[0] + 1.0f);
            th[1] = num[1] * __builtin_amdgcn_rcpf(e2[1] + 1.0f);
    return x + qh * th;
}

// compiler-only fence (R14-proven)
#define LDS_FENCE() asm volatile("" ::: "memory")

// Combo kernel: R16's packed-f2v 2-tile pairing (VALU -30%, load stalls
// amortized 2x) + R19's 16B-aligned transpose reads (DS -40%, conflict-free)
// + R14 fence discipline. f2v skew-12 region (stride 96 f2v): writes
// xp[j*96+blk*12+row] = b64 across 16 banks/phase; reads &xp[row*96+blk*12]
// 16B-aligned -> 4x ds_read_b128 per transpose, 2-way alias = free.
__global__ __launch_bounds__(256) void jpeg_kernel(const float* __restrict__ x,
                                                   float* __restrict__ out) {
    __shared__ f2v xpose[4][768];     // 24576 B
    __shared__ float qtab[4][64];     // 0:qhL 1:rqL 2:qhC 3:rqC, [v*8+u]

    const int tid = threadIdx.x;
    const int wid = tid >> 6;
    const int lane = tid & 63;

    const int gw = blockIdx.x * 4 + wid;     // 0..8191
    const int bimg = gw >> 9;                // image 0..15 (pair: +16)
    const int rem = gw & 511;
    const int gh = rem >> 3;                 // 8-row strip index
    const int tx = rem & 7;                  // 64-col tile index

    const int blk = lane & 7;                // 8x8 block within tile
    const int row = lane >> 3;               // row within strip / freq v

    const size_t off = (size_t)bimg * 3 * IMG_HW +
                       (size_t)(gh * 8 + row) * IMG_W + tx * 64 + blk * 8;
    const size_t toff = (size_t)16 * 3 * IMG_HW;
    const float* baseA = x + off;
    const float* baseB = baseA + toff;

    // issue all 6 global loads first; qtab init overlaps their latency
    const f8v RA = *(const f8v*)(baseA);
    const f8v GA = *(const f8v*)(baseA + IMG_HW);
    const f8v BA = *(const f8v*)(baseA + 2 * IMG_HW);
    const f8v RB = *(const f8v*)(baseB);
    const f8v GB = *(const f8v*)(baseB + IMG_HW);
    const f8v BB = *(const f8v*)(baseB + 2 * IMG_HW);

    {   // benign duplicate writes per wave; in-order DS per wave
        int u = lane & 7, v = lane >> 3;
        float ql = QLUM[u * 8 + v];
        float qc = QCHR[u * 8 + v];
        qtab[0][lane] = 0.5f * ql;
        qtab[1][lane] = __builtin_amdgcn_rcpf(ql);
        qtab[2][lane] = 0.5f * qc;
        qtab[3][lane] = __builtin_amdgcn_rcpf(qc);
    }
    LDS_FENCE();

    f2v* xp = xpose[wid];
    const int wbase = blk * 12 + row;        // write: xp[j*96 + wbase] (b64)
    const int rbase = row * 96 + blk * 12;   // read: 16B-aligned float4 pairs
    const int qrow = row * 8;

    // ---- forward color (packed pairs across the two tiles) ----
    f2v g0[8], g1[8], g2[8];
#pragma unroll
    for (int k = 0; k < 8; ++k) {
        f2v Rp; Rp[0] = RA[k]; Rp[1] = RB[k];
        f2v Gp; Gp[0] = GA[k]; Gp[1] = GB[k];
        f2v Bp; Bp[0] = BA[k]; Bp[1] = BB[k];
        g0[k] = 0.299f * Rp + 0.587f * Gp + 0.114f * Bp - 0.5f;
        g1[k] = -0.168736f * Rp - 0.331264f * Gp + 0.5f * Bp;
        g2[k] = 0.5f * Rp - 0.418688f * Gp - 0.081312f * Bp;
    }

    // transpose read burst: 4x float4 (b128), each = f2v pair {k, k+1}
#define XP_READ(g)                                              \
    {                                                           \
        float4 p0 = *(const float4*)&xp[rbase + 0];             \
        float4 p1 = *(const float4*)&xp[rbase + 2];             \
        float4 p2 = *(const float4*)&xp[rbase + 4];             \
        float4 p3 = *(const float4*)&xp[rbase + 6];             \
        g[0][0] = p0.x; g[0][1] = p0.y; g[1][0] = p0.z; g[1][1] = p0.w; \
        g[2][0] = p1.x; g[2][1] = p1.y; g[3][0] = p1.z; g[3][1] = p1.w; \
        g[4][0] = p2.x; g[4][1] = p2.y; g[5][0] = p2.z; g[5][1] = p2.w; \
        g[6][0] = p3.x; g[6][1] = p3.y; g[7][0] = p3.z; g[7][1] = p3.w; \
    }
#define XP_WRITE(g)                                             \
    {                                                           \
        _Pragma("unroll")                                       \
        for (int j = 0; j < 8; ++j) xp[j * 96 + wbase] = g[j];  \
    }
#define SOFTQ8(g, qhT, rqT)                                     \
    {                                                           \
        float4 qa = *(const float4*)&qtab[qhT][qrow];           \
        float4 qb = *(const float4*)&qtab[qhT][qrow + 4];       \
        float4 ra = *(const float4*)&qtab[rqT][qrow];           \
        float4 rb = *(const float4*)&qtab[rqT][qrow + 4];       \
        g[0] = softq2(g[0], qa.x, ra.x); g[1] = softq2(g[1], qa.y, ra.y); \
        g[2] = softq2(g[2], qa.z, ra.z); g[3] = softq2(g[3], qa.w, ra.w); \
        g[4] = softq2(g[4], qb.x, rb.x); g[5] = softq2(g[5], qb.y, rb.y); \
        g[6] = softq2(g[6], qb.z, rb.z); g[7] = softq2(g[7], qb.w, rb.w); \
    }

    // ================= channel 0 (luma) =================
    fdct8p(g0);
    XP_WRITE(g0);
    LDS_FENCE();
    XP_READ(g0);
    LDS_FENCE();
    fdct8p(g0);
    SOFTQ8(g0, 0, 1);
    idct8p(g0);
    LDS_FENCE();
    XP_WRITE(g0);
    LDS_FENCE();
    XP_READ(g0);
    LDS_FENCE();
    idct8p(g0);

    // ================= channel 1 (Cb) =================
    fdct8p(g1);
    XP_WRITE(g1);
    LDS_FENCE();
    XP_READ(g1);
    LDS_FENCE();
    fdct8p(g1);
    SOFTQ8(g1, 2, 3);
    idct8p(g1);
    LDS_FENCE();
    XP_WRITE(g1);
    LDS_FENCE();
    XP_READ(g1);
    LDS_FENCE();
    idct8p(g1);

    // ================= channel 2 (Cr) =================
    fdct8p(g2);
    XP_WRITE(g2);
    LDS_FENCE();
    XP_READ(g2);
    LDS_FENCE();
    fdct8p(g2);
    SOFTQ8(g2, 2, 3);
    idct8p(g2);
    LDS_FENCE();
    XP_WRITE(g2);
    LDS_FENCE();
    XP_READ(g2);
    LDS_FENCE();
    idct8p(g2);

    // ---- inverse color (packed) + split + coalesced stores ----
    const f2v vzero = {0.0f, 0.0f};
    const f2v vone  = {1.0f, 1.0f};
    f8v RoA, GoA, BoA, RoB, GoB, BoB;
#pragma unroll
    for (int k = 0; k < 8; ++k) {
        f2v Y  = g0[k] + 0.5f;
        f2v Cb = g1[k];
        f2v Cr = g2[k];
        f2v R = Y + 1.402f * Cr;
        f2v G = Y - 0.344136f * Cb - 0.714136f * Cr;
        f2v B = Y + 1.772f * Cb;
        R = __builtin_elementwise_min(__builtin_elementwise_max(R, vzero), vone);
        G = __builtin_elementwise_min(__builtin_elementwise_max(G, vzero), vone);
        B = __builtin_elementwise_min(__builtin_elementwise_max(B, vzero), vone);
        RoA[k] = R[0]; RoB[k] = R[1];
        GoA[k] = G[0]; GoB[k] = G[1];
        BoA[k] = B[0]; BoB[k] = B[1];
    }
    float* oA = out + off;
    float* oB = oA + toff;
    *(f8v*)(oA) = RoA;
    *(f8v*)(oA + IMG_HW) = GoA;
    *(f8v*)(oA + 2 * IMG_HW) = BoA;
    *(f8v*)(oB) = RoB;
    *(f8v*)(oB + IMG_HW) = GoB;
    *(f8v*)(oB + 2 * IMG_HW) = BoB;
}

extern "C" void kernel_launch(void* const* d_in, const int* in_sizes, int n_in,
                              void* d_out, int out_size, void* d_ws, size_t ws_size,
                              hipStream_t stream) {
    const float* x = (const float*)d_in[0];
    float* out = (float*)d_out;
    // 8192 waves x 2 tiles = 16384 tiles (32 images x 512 tiles each)
    const int n_wg = 2048;
    hipLaunchKernelGGL(jpeg_kernel, dim3(n_wg), dim3(256), 0, stream, x, out);
}